// Round 3
// baseline (366.136 us; speedup 1.0000x reference)
//
#include <hip/hip_runtime.h>
#include <hip/hip_fp16.h>

#define N_NODES 100000
#define N_EDGES 1600000
#define IN_DIM  165
#define HIDDEN  128
#define OUT_DIM 2

#define NBKT 196        // ceil(100000/512) buckets of 512 nodes
#define CHUNK 4096      // edges per partition block
#define NCHUNK ((N_EDGES + CHUNK - 1) / CHUNK)   // 391
#define PADCAP 10240    // arena slots per bucket (mean 8163, sigma ~90 -> 23 sigma slack)
#define KPAD 176        // 5*32 + 16
#define NSLICE 8        // feature slices of 16 (one per XCD)

typedef _Float16 half8_t __attribute__((ext_vector_type(8)));
typedef _Float16 half4_t __attribute__((ext_vector_type(4)));
typedef float floatx4 __attribute__((ext_vector_type(4)));
typedef float floatx4_a4 __attribute__((ext_vector_type(4), aligned(4)));  // under-aligned vec load

// ---------------- phase 1: chunk hist -> claim -> direct scatter into padded arena ----
// entry = src | (dst&511)<<17  (26 bits)

__global__ __launch_bounds__(512) void k_part2(const int* __restrict__ src,
                                               const int* __restrict__ dst,
                                               int* __restrict__ bcnt,
                                               unsigned* __restrict__ arena) {
    __shared__ int hist[256];
    __shared__ int gbase[256];

    int t = threadIdx.x;
    int e0 = blockIdx.x * CHUNK;
    int nE = N_EDGES - e0; if (nE > CHUNK) nE = CHUNK;
    int n4 = nE >> 2;                       // N_EDGES % 4 == 0, so no scalar tail
    const int4* dst4 = (const int4*)(dst + e0);
    const int4* src4 = (const int4*)(src + e0);

    if (t < 256) hist[t] = 0;
    __syncthreads();

    for (int i = t; i < n4; i += 512) {
        int4 d = dst4[i];
        atomicAdd(&hist[d.x >> 9], 1);
        atomicAdd(&hist[d.y >> 9], 1);
        atomicAdd(&hist[d.z >> 9], 1);
        atomicAdd(&hist[d.w >> 9], 1);
    }
    __syncthreads();

    if (t < NBKT) gbase[t] = t * PADCAP + atomicAdd(&bcnt[t], hist[t]);
    if (t < 256) hist[t] = 0;   // reuse as rank counter
    __syncthreads();

    for (int i = t; i < n4; i += 512) {
        int4 d = dst4[i];
        int4 s = src4[i];
        #pragma unroll
        for (int j = 0; j < 4; j++) {
            int dd = (j == 0) ? d.x : (j == 1) ? d.y : (j == 2) ? d.z : d.w;
            int ss = (j == 0) ? s.x : (j == 1) ? s.y : (j == 2) ? s.z : s.w;
            int bk = dd >> 9;
            unsigned entry = (unsigned)ss | ((unsigned)(dd & 511) << 17);
            int idx = atomicAdd(&hist[bk], 1);
            arena[gbase[bk] + idx] = entry;
        }
    }
}

// ---------------- tiny scan of bucket totals -> dense bucket bases ----------------

__global__ __launch_bounds__(256) void k_btot(const int* __restrict__ bcnt,
                                              int* __restrict__ bucketptr) {
    __shared__ int wsum[4];
    int t = threadIdx.x, lane = t & 63, wid = t >> 6;
    int v = (t < NBKT) ? bcnt[t] : 0;
    int inc = v;
    #pragma unroll
    for (int off = 1; off < 64; off <<= 1) {
        int y = __shfl_up(inc, off);
        if (lane >= off) inc += y;
    }
    if (lane == 63) wsum[wid] = inc;
    __syncthreads();
    if (t == 0) {
        int acc = 0;
        #pragma unroll
        for (int w = 0; w < 4; w++) { int tv = wsum[w]; wsum[w] = acc; acc += tv; }
    }
    __syncthreads();
    int excl = wsum[wid] + inc - v;
    if (t <= NBKT) bucketptr[t] = (t < NBKT) ? excl : N_EDGES;
}

// ---------------- phase 2: per-bucket sort; produces rowptr + dinv + csr ----------------

__global__ __launch_bounds__(1024) void k_sort3(const unsigned* __restrict__ arena,
                                                const int* __restrict__ bcnt,
                                                const int* __restrict__ bucketptr,
                                                int* __restrict__ csr,
                                                int* __restrict__ rowptr,
                                                float* __restrict__ dinv) {
    __shared__ int cnt[512];
    __shared__ int cur[512];
    __shared__ int wsum[4];
    int b = blockIdx.x;
    int n0 = b << 9;
    int t = threadIdx.x;
    int lane = t & 63, wid = t >> 6;
    int total = bcnt[b];
    int abase = b * PADCAP;        // PADCAP*4 bytes aligned -> int4-safe base
    int dbase = bucketptr[b];
    int nt4 = total >> 2;
    const uint4* arena4 = (const uint4*)(arena + abase);

    if (t < 512) cnt[t] = 0;
    __syncthreads();
    for (int p = t; p < nt4; p += 1024) {
        uint4 e = arena4[p];
        atomicAdd(&cnt[e.x >> 17], 1);
        atomicAdd(&cnt[e.y >> 17], 1);
        atomicAdd(&cnt[e.z >> 17], 1);
        atomicAdd(&cnt[e.w >> 17], 1);
    }
    {
        int p = (nt4 << 2) + t;
        if (p < total) atomicAdd(&cnt[arena[abase + p] >> 17], 1);
    }
    __syncthreads();

    // 512-entry exclusive scan using first 256 threads (thread t owns locals 2t, 2t+1)
    int c0 = 0, c1 = 0, s = 0, inc = 0;
    if (t < 256) {
        c0 = cnt[2 * t];
        c1 = cnt[2 * t + 1];
        s = c0 + c1;
        inc = s;
        #pragma unroll
        for (int off = 1; off < 64; off <<= 1) {
            int y = __shfl_up(inc, off);
            if (lane >= off) inc += y;
        }
        if (lane == 63) wsum[wid] = inc;
    }
    __syncthreads();
    if (t == 0) {
        int acc = 0;
        #pragma unroll
        for (int w = 0; w < 4; w++) { int tv = wsum[w]; wsum[w] = acc; acc += tv; }
    }
    __syncthreads();
    if (t < 256) {
        int base = dbase + wsum[wid] + (inc - s);
        cur[2 * t] = base;
        cur[2 * t + 1] = base + c0;
        int node0 = n0 + 2 * t;
        if (node0 < N_NODES) {
            rowptr[node0] = base;
            dinv[node0] = rsqrtf((float)(c0 + 1));
        }
        if (node0 + 1 < N_NODES) {
            rowptr[node0 + 1] = base + c0;
            dinv[node0 + 1] = rsqrtf((float)(c1 + 1));
        }
    }
    if (b == NBKT - 1 && t == 0) rowptr[N_NODES] = N_EDGES;
    __syncthreads();

    for (int p = t; p < nt4; p += 1024) {
        uint4 e = arena4[p];
        #pragma unroll
        for (int j = 0; j < 4; j++) {
            unsigned entry = (j == 0) ? e.x : (j == 1) ? e.y : (j == 2) ? e.z : e.w;
            int local = (int)(entry >> 17);
            int sv = (int)(entry & 0x1FFFFu);
            int pos = atomicAdd(&cur[local], 1);
            csr[pos] = sv;
        }
    }
    {
        int p = (nt4 << 2) + t;
        if (p < total) {
            unsigned entry = arena[abase + p];
            int local = (int)(entry >> 17);
            int sv = (int)(entry & 0x1FFFFu);
            int pos = atomicAdd(&cur[local], 1);
            csr[pos] = sv;
        }
    }
}

// ---------------- W1 transpose to fp16 [col][KPAD] ----------------

__global__ void k_w1t(const float* __restrict__ W1, _Float16* __restrict__ w1t) {
    int idx = blockIdx.x * 256 + threadIdx.x;
    if (idx < HIDDEN * KPAD) {
        int c = idx / KPAD, k = idx - c * KPAD;
        float v = (k < IN_DIM) ? W1[k * HIDDEN + c] : 0.f;
        w1t[idx] = (_Float16)v;
    }
}

// ---------------- GEMM1 (f16 MFMA): h1s = dinv * (x @ W1), fp16 SLICED out ----------------
// Output layout: h1s[slice][node][16] where slice = col/16. 32B contiguous per (slice,node).

__global__ __launch_bounds__(256) void k_gemm1(const float* __restrict__ x,
                                               const _Float16* __restrict__ w1t,
                                               const float* __restrict__ dinv,
                                               _Float16* __restrict__ h1s) {
    int t = threadIdx.x;
    int wid = t >> 6, lane = t & 63;
    int row0 = (blockIdx.x * 4 + wid) * 16;
    if (row0 >= N_NODES) return;
    int m = lane & 15;
    int quad = lane >> 4;
    const float* xrow = x + (size_t)(row0 + m) * IN_DIM;

    floatx4 acc[8];
    #pragma unroll
    for (int i = 0; i < 8; i++) acc[i] = (floatx4)(0.f);

    #pragma unroll
    for (int kc = 0; kc < 5; kc++) {
        int kb = kc * 32 + quad * 8;       // max 152; +7 = 159 < 165 -> always in-row
        floatx4_a4 va = *(const floatx4_a4*)(xrow + kb);
        floatx4_a4 vb = *(const floatx4_a4*)(xrow + kb + 4);
        half8_t a;
        #pragma unroll
        for (int j = 0; j < 4; j++) a[j] = (_Float16)va[j];
        #pragma unroll
        for (int j = 0; j < 4; j++) a[4 + j] = (_Float16)vb[j];
        #pragma unroll
        for (int cb = 0; cb < 8; cb++) {
            int col = cb * 16 + m;
            half8_t bf = *(const half8_t*)&w1t[col * KPAD + kb];
            acc[cb] = __builtin_amdgcn_mfma_f32_16x16x32_f16(a, bf, acc[cb], 0, 0, 0);
        }
    }
    // K tail: 160..164 via 16x16x16 (k = quad*4 + j) -- scalar guarded loads (OOB-safe)
    {
        int kb = 160 + quad * 4;
        half4_t a;
        #pragma unroll
        for (int j = 0; j < 4; j++)
            a[j] = (kb + j < IN_DIM) ? (_Float16)xrow[kb + j] : (_Float16)0.f;
        #pragma unroll
        for (int cb = 0; cb < 8; cb++) {
            int col = cb * 16 + m;
            half4_t bf = *(const half4_t*)&w1t[col * KPAD + kb];
            acc[cb] = __builtin_amdgcn_mfma_f32_16x16x16f16(a, bf, acc[cb], 0, 0, 0);
        }
    }
    // epilogue: scale by dinv[row], store fp16 sliced (C/D: col=lane&15, row=quad*4+reg)
    float dv[4];
    #pragma unroll
    for (int r = 0; r < 4; r++) dv[r] = dinv[row0 + quad * 4 + r];
    #pragma unroll
    for (int cb = 0; cb < 8; cb++) {
        #pragma unroll
        for (int r = 0; r < 4; r++) {
            h1s[((size_t)cb * N_NODES + (row0 + quad * 4 + r)) * 16 + m] =
                (_Float16)(acc[cb][r] * dv[r]);
        }
    }
}

// ---------------- agg1, feature-sliced: slice = blockIdx%8 -> pins slice to XCD ----------
// Each XCD reads only its 3.2MB h1 slice (L2-resident). Per block: 4 waves x 2 nodes.
// Wave layout: half = lane>>5 selects node; within 32-lane half: fl = lane&1 owns
// 8 features (16B gather), es = (lane&31)>>1 is edge slot 0..15.
// Emits per-slice partial W2-dot into h2part[slice][node]; k_h2sum finishes.

__global__ __launch_bounds__(256) void k_agg1(const _Float16* __restrict__ h1,
                                              const int* __restrict__ rowptr,
                                              const int* __restrict__ csr,
                                              const float* __restrict__ dinv,
                                              const float* __restrict__ b1,
                                              const float* __restrict__ W2,
                                              float2* __restrict__ h2part) {
    int t = threadIdx.x;
    int wid = t >> 6, lane = t & 63;
    int s  = blockIdx.x & 7;        // slice == XCD (round-robin dispatch)
    int g  = blockIdx.x >> 3;       // node group
    int half = lane >> 5;
    int l  = lane & 31;
    int fl = l & 1;                 // feature sub-lane: features fl*8..fl*8+7 of slice
    int es = l >> 1;                // edge slot 0..15
    int node = g * 8 + wid * 2 + half;

    const _Float16* hs = h1 + (size_t)s * N_NODES * 16;

    float acc[8];
    {   // self term, counted once (edge-slot 0)
        half8_t v = *(const half8_t*)(hs + (size_t)node * 16 + fl * 8);
        #pragma unroll
        for (int j = 0; j < 8; j++) acc[j] = (es == 0) ? (float)v[j] : 0.f;
    }

    int p0 = rowptr[node], p1 = rowptr[node + 1];
    for (int p = p0 + es; p < p1; p += 16) {
        int sv = __builtin_nontemporal_load(&csr[p]);   // stream csr, keep h1 slice resident
        half8_t v = *(const half8_t*)(hs + (size_t)sv * 16 + fl * 8);
        #pragma unroll
        for (int j = 0; j < 8; j++) acc[j] += (float)v[j];
    }

    // reduce across 16 edge slots (lane bits 1..4), stay within 32-lane half
    #pragma unroll
    for (int j = 0; j < 8; j++) {
        acc[j] += __shfl_xor(acc[j], 2);
        acc[j] += __shfl_xor(acc[j], 4);
        acc[j] += __shfl_xor(acc[j], 8);
        acc[j] += __shfl_xor(acc[j], 16);
    }

    float di = dinv[node];
    // z = relu(di*acc + b1[slice]), partial dot with W2 rows of this slice
    float4 bb0 = ((const float4*)b1)[(s * 16 + fl * 8) >> 2];
    float4 bb1 = ((const float4*)b1)[((s * 16 + fl * 8) >> 2) + 1];
    float bv[8] = {bb0.x, bb0.y, bb0.z, bb0.w, bb1.x, bb1.y, bb1.z, bb1.w};
    float a0 = 0.f, a1 = 0.f;
    #pragma unroll
    for (int j = 0; j < 8; j++) {
        float z = fmaf(di, acc[j], bv[j]);
        float r = fmaxf(z, 0.f);
        float2 w = ((const float2*)W2)[s * 16 + fl * 8 + j];
        a0 = fmaf(r, w.x, a0);
        a1 = fmaf(r, w.y, a1);
    }
    a0 += __shfl_xor(a0, 1);
    a1 += __shfl_xor(a1, 1);
    if (l == 0) h2part[(size_t)s * N_NODES + node] = make_float2(a0, a1);
}

// ---------------- h2sum: h2s[n] = dinv[n] * sum_s h2part[s][n] ----------------

__global__ __launch_bounds__(256) void k_h2sum(const float2* __restrict__ h2part,
                                               const float* __restrict__ dinv,
                                               float2* __restrict__ h2s) {
    int n = blockIdx.x * 256 + threadIdx.x;
    if (n >= N_NODES) return;
    float ax = 0.f, ay = 0.f;
    #pragma unroll
    for (int s = 0; s < NSLICE; s++) {
        float2 v = h2part[(size_t)s * N_NODES + n];
        ax += v.x;
        ay += v.y;
    }
    float di = dinv[n];
    h2s[n] = make_float2(di * ax, di * ay);
}

// ---------------- agg2: out = b2 + dinv_i*(h2s_i + sum h2s_src) ----------------
// 16 lanes per node (wave = 4 nodes): lane-parallel gathers + xor-shuffle reduce.

__global__ __launch_bounds__(256) void k_agg2(const float2* __restrict__ h2s,
                                              const int* __restrict__ rowptr,
                                              const int* __restrict__ csr,
                                              const float* __restrict__ dinv,
                                              const float* __restrict__ b2,
                                              float2* __restrict__ out) {
    int wid = threadIdx.x >> 6, lane = threadIdx.x & 63;
    int sub = lane >> 4, el = lane & 15;
    int node = blockIdx.x * 16 + wid * 4 + sub;   // grid 6250 * 16 = 100000 exactly
    int p0 = rowptr[node], p1 = rowptr[node + 1];
    float ax = 0.f, ay = 0.f;
    for (int p = p0 + el; p < p1; p += 16) {
        float2 g = h2s[csr[p]];
        ax += g.x;
        ay += g.y;
    }
    #pragma unroll
    for (int off = 8; off; off >>= 1) {
        ax += __shfl_xor(ax, off);
        ay += __shfl_xor(ay, off);
    }
    if (el == 0) {
        float2 self = h2s[node];
        float di = dinv[node];
        out[node] = make_float2(fmaf(di, self.x + ax, b2[0]),
                                fmaf(di, self.y + ay, b2[1]));
    }
}

// ---------------- launch ----------------

extern "C" void kernel_launch(void* const* d_in, const int* in_sizes, int n_in,
                              void* d_out, int out_size, void* d_ws, size_t ws_size,
                              hipStream_t stream) {
    const float* x  = (const float*)d_in[0];
    const int*   ei = (const int*)d_in[1];
    const float* W1 = (const float*)d_in[2];
    const float* b1 = (const float*)d_in[3];
    const float* W2 = (const float*)d_in[4];
    const float* b2 = (const float*)d_in[5];
    float* out = (float*)d_out;

    const int* src = ei;
    const int* dst = ei + N_EDGES;

    char* ws = (char*)d_ws;
    size_t off = 0;
    auto alloc = [&](size_t bytes) -> void* {
        void* p = ws + off;
        off += (bytes + 255) & ~(size_t)255;
        return p;
    };
    _Float16* h1s    = (_Float16*)alloc((size_t)N_NODES * HIDDEN * 2);  // 25.6 MB (sliced)
    float*    dinv   = (float*)   alloc((size_t)N_NODES * 4);
    int*      rowptr = (int*)     alloc((size_t)(N_NODES + 1) * 4);
    int*      bcnt   = (int*)     alloc((size_t)NBKT * 4);
    int*      bktptr = (int*)     alloc((size_t)(NBKT + 1) * 4);
    unsigned* arena  = (unsigned*)alloc((size_t)NBKT * PADCAP * 4);     // 8.0 MB
    int*      csr    = (int*)     alloc((size_t)N_EDGES * 4);           // 6.4 MB
    _Float16* w1t    = (_Float16*)alloc((size_t)HIDDEN * KPAD * 2);     // 45 KB
    float2*   h2s    = (float2*)  alloc((size_t)N_NODES * 8);
    // h2part (6.4 MB) aliases arena: arena is dead after k_sort3, h2part born at k_agg1
    float2*   h2part = (float2*)arena;

    (void)hipMemsetAsync(bcnt, 0, (size_t)NBKT * 4, stream);
    k_w1t<<<(HIDDEN * KPAD + 255) / 256, 256, 0, stream>>>(W1, w1t);
    k_part2<<<NCHUNK, 512, 0, stream>>>(src, dst, bcnt, arena);
    k_btot<<<1, 256, 0, stream>>>(bcnt, bktptr);
    k_sort3<<<NBKT, 1024, 0, stream>>>(arena, bcnt, bktptr, csr, rowptr, dinv);
    k_gemm1<<<(N_NODES / 16 + 3) / 4, 256, 0, stream>>>(x, w1t, dinv, h1s);
    k_agg1<<<(N_NODES / 8) * NSLICE, 256, 0, stream>>>(h1s, rowptr, csr, dinv, b1, W2, h2part);
    k_h2sum<<<(N_NODES + 255) / 256, 256, 0, stream>>>(h2part, dinv, h2s);
    k_agg2<<<N_NODES / 16, 256, 0, stream>>>(h2s, rowptr, csr, dinv, b2, (float2*)out);
}

// Round 4
// 257.049 us; speedup vs baseline: 1.4244x; 1.4244x over previous
//
#include <hip/hip_runtime.h>
#include <hip/hip_fp16.h>

#define N_NODES 100000
#define N_EDGES 1600000
#define IN_DIM  165
#define HIDDEN  128
#define OUT_DIM 2

#define NBKT 196        // ceil(100000/512) buckets of 512 nodes
#define CHUNK 4096      // edges per partition block
#define NCHUNK ((N_EDGES + CHUNK - 1) / CHUNK)   // 391
#define PADCAP 10240    // arena/csr slots per bucket (mean 8163, sigma ~90)
#define KPAD 176        // 5*32 + 16

typedef _Float16 half8_t __attribute__((ext_vector_type(8)));
typedef _Float16 half4_t __attribute__((ext_vector_type(4)));
typedef float floatx4 __attribute__((ext_vector_type(4)));
typedef float floatx4_a4 __attribute__((ext_vector_type(4), aligned(4)));  // under-aligned vec load

// ---------------- phase 1: chunk hist -> claim -> direct scatter into padded arena ----
// entry = src | (dst&511)<<17  (26 bits)

__global__ __launch_bounds__(512) void k_part2(const int* __restrict__ src,
                                               const int* __restrict__ dst,
                                               int* __restrict__ bcnt,
                                               unsigned* __restrict__ arena) {
    __shared__ int hist[256];
    __shared__ int gbase[256];

    int t = threadIdx.x;
    int e0 = blockIdx.x * CHUNK;
    int nE = N_EDGES - e0; if (nE > CHUNK) nE = CHUNK;
    int n4 = nE >> 2;                       // N_EDGES % 4 == 0, so no scalar tail
    const int4* dst4 = (const int4*)(dst + e0);
    const int4* src4 = (const int4*)(src + e0);

    if (t < 256) hist[t] = 0;
    __syncthreads();

    for (int i = t; i < n4; i += 512) {
        int4 d = dst4[i];
        atomicAdd(&hist[d.x >> 9], 1);
        atomicAdd(&hist[d.y >> 9], 1);
        atomicAdd(&hist[d.z >> 9], 1);
        atomicAdd(&hist[d.w >> 9], 1);
    }
    __syncthreads();

    if (t < NBKT) gbase[t] = t * PADCAP + atomicAdd(&bcnt[t], hist[t]);
    if (t < 256) hist[t] = 0;   // reuse as rank counter
    __syncthreads();

    for (int i = t; i < n4; i += 512) {
        int4 d = dst4[i];
        int4 s = src4[i];
        #pragma unroll
        for (int j = 0; j < 4; j++) {
            int dd = (j == 0) ? d.x : (j == 1) ? d.y : (j == 2) ? d.z : d.w;
            int ss = (j == 0) ? s.x : (j == 1) ? s.y : (j == 2) ? s.z : s.w;
            int bk = dd >> 9;
            unsigned entry = (unsigned)ss | ((unsigned)(dd & 511) << 17);
            int idx = atomicAdd(&hist[bk], 1);
            arena[gbase[bk] + idx] = entry;
        }
    }
}

// ---------------- phase 2: per-bucket sort into PADDED csr; rowstart/rowend + dinv ------
// csr segment for bucket b lives at [b*PADCAP, b*PADCAP+total). No cross-bucket scan
// needed (k_btot eliminated) -> one fewer launch + device drain.

__global__ __launch_bounds__(1024) void k_sort4(const unsigned* __restrict__ arena,
                                                const int* __restrict__ bcnt,
                                                int* __restrict__ csr,
                                                int* __restrict__ rowstart,
                                                int* __restrict__ rowend,
                                                float* __restrict__ dinv) {
    __shared__ int cnt[512];
    __shared__ int cur[512];
    __shared__ int wsum[4];
    int b = blockIdx.x;
    int n0 = b << 9;
    int t = threadIdx.x;
    int lane = t & 63, wid = t >> 6;
    int total = bcnt[b];
    int abase = b * PADCAP;        // PADCAP*4 bytes aligned -> int4-safe base
    int dbase = b * PADCAP;        // csr uses the same padded layout
    int nt4 = total >> 2;
    const uint4* arena4 = (const uint4*)(arena + abase);

    if (t < 512) cnt[t] = 0;
    __syncthreads();
    for (int p = t; p < nt4; p += 1024) {
        uint4 e = arena4[p];
        atomicAdd(&cnt[e.x >> 17], 1);
        atomicAdd(&cnt[e.y >> 17], 1);
        atomicAdd(&cnt[e.z >> 17], 1);
        atomicAdd(&cnt[e.w >> 17], 1);
    }
    {
        int p = (nt4 << 2) + t;
        if (p < total) atomicAdd(&cnt[arena[abase + p] >> 17], 1);
    }
    __syncthreads();

    // 512-entry exclusive scan using first 256 threads (thread t owns locals 2t, 2t+1)
    int c0 = 0, c1 = 0, s = 0, inc = 0;
    if (t < 256) {
        c0 = cnt[2 * t];
        c1 = cnt[2 * t + 1];
        s = c0 + c1;
        inc = s;
        #pragma unroll
        for (int off = 1; off < 64; off <<= 1) {
            int y = __shfl_up(inc, off);
            if (lane >= off) inc += y;
        }
        if (lane == 63) wsum[wid] = inc;
    }
    __syncthreads();
    if (t == 0) {
        int acc = 0;
        #pragma unroll
        for (int w = 0; w < 4; w++) { int tv = wsum[w]; wsum[w] = acc; acc += tv; }
    }
    __syncthreads();
    if (t < 256) {
        int base = dbase + wsum[wid] + (inc - s);
        cur[2 * t] = base;
        cur[2 * t + 1] = base + c0;
        int node0 = n0 + 2 * t;
        if (node0 < N_NODES) {
            rowstart[node0] = base;
            rowend[node0] = base + c0;
            dinv[node0] = rsqrtf((float)(c0 + 1));
        }
        if (node0 + 1 < N_NODES) {
            rowstart[node0 + 1] = base + c0;
            rowend[node0 + 1] = base + c0 + c1;
            dinv[node0 + 1] = rsqrtf((float)(c1 + 1));
        }
    }
    __syncthreads();

    for (int p = t; p < nt4; p += 1024) {
        uint4 e = arena4[p];
        #pragma unroll
        for (int j = 0; j < 4; j++) {
            unsigned entry = (j == 0) ? e.x : (j == 1) ? e.y : (j == 2) ? e.z : e.w;
            int local = (int)(entry >> 17);
            int sv = (int)(entry & 0x1FFFFu);
            int pos = atomicAdd(&cur[local], 1);
            csr[pos] = sv;
        }
    }
    {
        int p = (nt4 << 2) + t;
        if (p < total) {
            unsigned entry = arena[abase + p];
            int local = (int)(entry >> 17);
            int sv = (int)(entry & 0x1FFFFu);
            int pos = atomicAdd(&cur[local], 1);
            csr[pos] = sv;
        }
    }
}

// ---------------- W1 transpose to fp16 [col][KPAD] ----------------

__global__ void k_w1t(const float* __restrict__ W1, _Float16* __restrict__ w1t) {
    int idx = blockIdx.x * 256 + threadIdx.x;
    if (idx < HIDDEN * KPAD) {
        int c = idx / KPAD, k = idx - c * KPAD;
        float v = (k < IN_DIM) ? W1[k * HIDDEN + c] : 0.f;
        w1t[idx] = (_Float16)v;
    }
}

// ---------------- GEMM1 (f16 MFMA): h1s = dinv * (x @ W1), fp16 row-major out ----------------

__global__ __launch_bounds__(256) void k_gemm1(const float* __restrict__ x,
                                               const _Float16* __restrict__ w1t,
                                               const float* __restrict__ dinv,
                                               _Float16* __restrict__ h1s) {
    int t = threadIdx.x;
    int wid = t >> 6, lane = t & 63;
    int row0 = (blockIdx.x * 4 + wid) * 16;
    if (row0 >= N_NODES) return;
    int m = lane & 15;
    int quad = lane >> 4;
    const float* xrow = x + (size_t)(row0 + m) * IN_DIM;

    floatx4 acc[8];
    #pragma unroll
    for (int i = 0; i < 8; i++) acc[i] = (floatx4)(0.f);

    #pragma unroll
    for (int kc = 0; kc < 5; kc++) {
        int kb = kc * 32 + quad * 8;       // max 152; +7 = 159 < 165 -> always in-row
        floatx4_a4 va = *(const floatx4_a4*)(xrow + kb);
        floatx4_a4 vb = *(const floatx4_a4*)(xrow + kb + 4);
        half8_t a;
        #pragma unroll
        for (int j = 0; j < 4; j++) a[j] = (_Float16)va[j];
        #pragma unroll
        for (int j = 0; j < 4; j++) a[4 + j] = (_Float16)vb[j];
        #pragma unroll
        for (int cb = 0; cb < 8; cb++) {
            int col = cb * 16 + m;
            half8_t bf = *(const half8_t*)&w1t[col * KPAD + kb];
            acc[cb] = __builtin_amdgcn_mfma_f32_16x16x32_f16(a, bf, acc[cb], 0, 0, 0);
        }
    }
    // K tail: 160..164 via 16x16x16 (k = quad*4 + j) -- scalar guarded loads (OOB-safe)
    {
        int kb = 160 + quad * 4;
        half4_t a;
        #pragma unroll
        for (int j = 0; j < 4; j++)
            a[j] = (kb + j < IN_DIM) ? (_Float16)xrow[kb + j] : (_Float16)0.f;
        #pragma unroll
        for (int cb = 0; cb < 8; cb++) {
            int col = cb * 16 + m;
            half4_t bf = *(const half4_t*)&w1t[col * KPAD + kb];
            acc[cb] = __builtin_amdgcn_mfma_f32_16x16x16f16(a, bf, acc[cb], 0, 0, 0);
        }
    }
    // epilogue: scale by dinv[row], store fp16 (C/D: col=lane&15, row=quad*4+reg)
    float dv[4];
    #pragma unroll
    for (int r = 0; r < 4; r++) dv[r] = dinv[row0 + quad * 4 + r];
    #pragma unroll
    for (int cb = 0; cb < 8; cb++) {
        #pragma unroll
        for (int r = 0; r < 4; r++) {
            h1s[(size_t)(row0 + quad * 4 + r) * HIDDEN + cb * 16 + m] =
                (_Float16)(acc[cb][r] * dv[r]);
        }
    }
}

// ---------------- Fused agg1 + bias + ReLU + W2 (128->2) ----------------
// One wave per node, 16 feature-lanes x 4 edge-slots, 16B/lane half8 gathers.
// 4-deep pipeline: 4 gathers (4KB/wave) in flight to probe the L2-miss concurrency
// limit. csr loads nontemporal so the 6.4MB index stream doesn't evict the h1
// working set from L2.

__global__ __launch_bounds__(256) void k_agg1(const _Float16* __restrict__ h1,
                                              const int* __restrict__ rowstart,
                                              const int* __restrict__ rowend,
                                              const int* __restrict__ csr,
                                              const float* __restrict__ dinv,
                                              const float* __restrict__ b1,
                                              const float* __restrict__ W2,
                                              float2* __restrict__ h2s) {
    int wid = threadIdx.x >> 6, lane = threadIdx.x & 63;
    int el = lane & 15;        // feature slot: owns features el*8 .. el*8+7
    int es = lane >> 4;        // edge slot 0..3
    int node = blockIdx.x * 4 + wid;

    float acc[8];
    // self term counted once (edge-slot 0)
    {
        half8_t v = *(const half8_t*)(h1 + (size_t)node * HIDDEN + el * 8);
        #pragma unroll
        for (int j = 0; j < 8; j++) acc[j] = (es == 0) ? (float)v[j] : 0.f;
    }

    int p0 = rowstart[node], p1 = rowend[node];
    int p = p0 + es;
    // 4-deep unroll: 4 gathers in flight per lane
    for (; p + 12 < p1; p += 16) {
        int s0 = __builtin_nontemporal_load(&csr[p]);
        int s1 = __builtin_nontemporal_load(&csr[p + 4]);
        int s2 = __builtin_nontemporal_load(&csr[p + 8]);
        int s3 = __builtin_nontemporal_load(&csr[p + 12]);
        half8_t v0 = *(const half8_t*)(h1 + (size_t)s0 * HIDDEN + el * 8);
        half8_t v1 = *(const half8_t*)(h1 + (size_t)s1 * HIDDEN + el * 8);
        half8_t v2 = *(const half8_t*)(h1 + (size_t)s2 * HIDDEN + el * 8);
        half8_t v3 = *(const half8_t*)(h1 + (size_t)s3 * HIDDEN + el * 8);
        #pragma unroll
        for (int j = 0; j < 8; j++) acc[j] += (float)v0[j];
        #pragma unroll
        for (int j = 0; j < 8; j++) acc[j] += (float)v1[j];
        #pragma unroll
        for (int j = 0; j < 8; j++) acc[j] += (float)v2[j];
        #pragma unroll
        for (int j = 0; j < 8; j++) acc[j] += (float)v3[j];
    }
    for (; p < p1; p += 4) {
        int s = __builtin_nontemporal_load(&csr[p]);
        half8_t v = *(const half8_t*)(h1 + (size_t)s * HIDDEN + el * 8);
        #pragma unroll
        for (int j = 0; j < 8; j++) acc[j] += (float)v[j];
    }

    // reduce across the 4 edge slots (lanes el, el+16, el+32, el+48)
    #pragma unroll
    for (int j = 0; j < 8; j++) {
        acc[j] += __shfl_xor(acc[j], 16);
        acc[j] += __shfl_xor(acc[j], 32);
    }

    float di = dinv[node];
    // z = relu(di*acc + b1), then partial dot with W2 (128x2)
    float4 bb0 = ((const float4*)b1)[el * 2];
    float4 bb1 = ((const float4*)b1)[el * 2 + 1];
    float bv[8] = {bb0.x, bb0.y, bb0.z, bb0.w, bb1.x, bb1.y, bb1.z, bb1.w};
    float a0 = 0.f, a1 = 0.f;
    #pragma unroll
    for (int j = 0; j < 8; j++) {
        float z = fmaf(di, acc[j], bv[j]);
        float r = fmaxf(z, 0.f);
        float2 w = ((const float2*)W2)[el * 8 + j];
        a0 = fmaf(r, w.x, a0);
        a1 = fmaf(r, w.y, a1);
    }
    #pragma unroll
    for (int off = 8; off; off >>= 1) {
        a0 += __shfl_xor(a0, off);
        a1 += __shfl_xor(a1, off);
    }
    if (lane == 0) h2s[node] = make_float2(di * a0, di * a1);
}

// ---------------- agg2: out = b2 + dinv_i*(h2s_i + sum h2s_src) ----------------
// 16 lanes per node (wave = 4 nodes): lane-parallel gathers + xor-shuffle reduce.

__global__ __launch_bounds__(256) void k_agg2(const float2* __restrict__ h2s,
                                              const int* __restrict__ rowstart,
                                              const int* __restrict__ rowend,
                                              const int* __restrict__ csr,
                                              const float* __restrict__ dinv,
                                              const float* __restrict__ b2,
                                              float2* __restrict__ out) {
    int wid = threadIdx.x >> 6, lane = threadIdx.x & 63;
    int sub = lane >> 4, el = lane & 15;
    int node = blockIdx.x * 16 + wid * 4 + sub;   // grid 6250 * 16 = 100000 exactly
    int p0 = rowstart[node], p1 = rowend[node];
    float ax = 0.f, ay = 0.f;
    for (int p = p0 + el; p < p1; p += 16) {
        float2 g = h2s[csr[p]];
        ax += g.x;
        ay += g.y;
    }
    #pragma unroll
    for (int off = 8; off; off >>= 1) {
        ax += __shfl_xor(ax, off);
        ay += __shfl_xor(ay, off);
    }
    if (el == 0) {
        float2 self = h2s[node];
        float di = dinv[node];
        out[node] = make_float2(fmaf(di, self.x + ax, b2[0]),
                                fmaf(di, self.y + ay, b2[1]));
    }
}

// ---------------- launch ----------------

extern "C" void kernel_launch(void* const* d_in, const int* in_sizes, int n_in,
                              void* d_out, int out_size, void* d_ws, size_t ws_size,
                              hipStream_t stream) {
    const float* x  = (const float*)d_in[0];
    const int*   ei = (const int*)d_in[1];
    const float* W1 = (const float*)d_in[2];
    const float* b1 = (const float*)d_in[3];
    const float* W2 = (const float*)d_in[4];
    const float* b2 = (const float*)d_in[5];
    float* out = (float*)d_out;

    const int* src = ei;
    const int* dst = ei + N_EDGES;

    char* ws = (char*)d_ws;
    size_t off = 0;
    auto alloc = [&](size_t bytes) -> void* {
        void* p = ws + off;
        off += (bytes + 255) & ~(size_t)255;
        return p;
    };
    _Float16* h1s      = (_Float16*)alloc((size_t)N_NODES * HIDDEN * 2);  // 25.6 MB
    float*    dinv     = (float*)   alloc((size_t)N_NODES * 4);
    int*      rowstart = (int*)     alloc((size_t)N_NODES * 4);
    int*      rowend   = (int*)     alloc((size_t)N_NODES * 4);
    int*      bcnt     = (int*)     alloc((size_t)NBKT * 4);
    unsigned* arena    = (unsigned*)alloc((size_t)NBKT * PADCAP * 4);     // 8.0 MB
    int*      csr      = (int*)     alloc((size_t)NBKT * PADCAP * 4);     // 8.0 MB padded
    _Float16* w1t      = (_Float16*)alloc((size_t)HIDDEN * KPAD * 2);     // 45 KB
    float2*   h2s      = (float2*)  alloc((size_t)N_NODES * 8);

    (void)hipMemsetAsync(bcnt, 0, (size_t)NBKT * 4, stream);
    k_w1t<<<(HIDDEN * KPAD + 255) / 256, 256, 0, stream>>>(W1, w1t);
    k_part2<<<NCHUNK, 512, 0, stream>>>(src, dst, bcnt, arena);
    k_sort4<<<NBKT, 1024, 0, stream>>>(arena, bcnt, csr, rowstart, rowend, dinv);
    k_gemm1<<<(N_NODES / 16 + 3) / 4, 256, 0, stream>>>(x, w1t, dinv, h1s);
    k_agg1<<<N_NODES / 4, 256, 0, stream>>>(h1s, rowstart, rowend, csr, dinv, b1, W2, h2s);
    k_agg2<<<N_NODES / 16, 256, 0, stream>>>(h2s, rowstart, rowend, csr, dinv, b2, (float2*)out);
}

// Round 5
// 242.572 us; speedup vs baseline: 1.5094x; 1.0597x over previous
//
#include <hip/hip_runtime.h>
#include <hip/hip_fp16.h>

#define N_NODES 100000
#define N_EDGES 1600000
#define IN_DIM  165
#define HIDDEN  128
#define OUT_DIM 2

#define NBKT 196        // ceil(100000/512) buckets of 512 nodes
#define CHUNK 4096      // edges per partition block
#define NCHUNK ((N_EDGES + CHUNK - 1) / CHUNK)   // 391
#define PADCAP 10240    // arena/csr slots per bucket (mean 8163, sigma ~90)
#define KPAD 176        // 5*32 + 16
#define GROWS 64        // x rows staged per gemm1 block

typedef _Float16 half8_t __attribute__((ext_vector_type(8)));
typedef _Float16 half4_t __attribute__((ext_vector_type(4)));
typedef float floatx4 __attribute__((ext_vector_type(4)));

// ---------------- phase 1: chunk hist -> claim -> direct scatter into padded arena ----
// entry = src | (dst&511)<<17  (26 bits)

__global__ __launch_bounds__(512) void k_part2(const int* __restrict__ src,
                                               const int* __restrict__ dst,
                                               int* __restrict__ bcnt,
                                               unsigned* __restrict__ arena) {
    __shared__ int hist[256];
    __shared__ int gbase[256];

    int t = threadIdx.x;
    int e0 = blockIdx.x * CHUNK;
    int nE = N_EDGES - e0; if (nE > CHUNK) nE = CHUNK;
    int n4 = nE >> 2;                       // N_EDGES % 4 == 0, so no scalar tail
    const int4* dst4 = (const int4*)(dst + e0);
    const int4* src4 = (const int4*)(src + e0);

    if (t < 256) hist[t] = 0;
    __syncthreads();

    for (int i = t; i < n4; i += 512) {
        int4 d = dst4[i];
        atomicAdd(&hist[d.x >> 9], 1);
        atomicAdd(&hist[d.y >> 9], 1);
        atomicAdd(&hist[d.z >> 9], 1);
        atomicAdd(&hist[d.w >> 9], 1);
    }
    __syncthreads();

    if (t < NBKT) gbase[t] = t * PADCAP + atomicAdd(&bcnt[t], hist[t]);
    if (t < 256) hist[t] = 0;   // reuse as rank counter
    __syncthreads();

    for (int i = t; i < n4; i += 512) {
        int4 d = dst4[i];
        int4 s = src4[i];
        #pragma unroll
        for (int j = 0; j < 4; j++) {
            int dd = (j == 0) ? d.x : (j == 1) ? d.y : (j == 2) ? d.z : d.w;
            int ss = (j == 0) ? s.x : (j == 1) ? s.y : (j == 2) ? s.z : s.w;
            int bk = dd >> 9;
            unsigned entry = (unsigned)ss | ((unsigned)(dd & 511) << 17);
            int idx = atomicAdd(&hist[bk], 1);
            arena[gbase[bk] + idx] = entry;
        }
    }
}

// ---------------- phase 2: per-bucket sort into PADDED csr; rowstart/rowend + dinv ------

__global__ __launch_bounds__(1024) void k_sort4(const unsigned* __restrict__ arena,
                                                const int* __restrict__ bcnt,
                                                int* __restrict__ csr,
                                                int* __restrict__ rowstart,
                                                int* __restrict__ rowend,
                                                float* __restrict__ dinv) {
    __shared__ int cnt[512];
    __shared__ int cur[512];
    __shared__ int wsum[4];
    int b = blockIdx.x;
    int n0 = b << 9;
    int t = threadIdx.x;
    int lane = t & 63, wid = t >> 6;
    int total = bcnt[b];
    int abase = b * PADCAP;        // PADCAP*4 bytes aligned -> int4-safe base
    int dbase = b * PADCAP;        // csr uses the same padded layout
    int nt4 = total >> 2;
    const uint4* arena4 = (const uint4*)(arena + abase);

    if (t < 512) cnt[t] = 0;
    __syncthreads();
    for (int p = t; p < nt4; p += 1024) {
        uint4 e = arena4[p];
        atomicAdd(&cnt[e.x >> 17], 1);
        atomicAdd(&cnt[e.y >> 17], 1);
        atomicAdd(&cnt[e.z >> 17], 1);
        atomicAdd(&cnt[e.w >> 17], 1);
    }
    {
        int p = (nt4 << 2) + t;
        if (p < total) atomicAdd(&cnt[arena[abase + p] >> 17], 1);
    }
    __syncthreads();

    // 512-entry exclusive scan using first 256 threads (thread t owns locals 2t, 2t+1)
    int c0 = 0, c1 = 0, s = 0, inc = 0;
    if (t < 256) {
        c0 = cnt[2 * t];
        c1 = cnt[2 * t + 1];
        s = c0 + c1;
        inc = s;
        #pragma unroll
        for (int off = 1; off < 64; off <<= 1) {
            int y = __shfl_up(inc, off);
            if (lane >= off) inc += y;
        }
        if (lane == 63) wsum[wid] = inc;
    }
    __syncthreads();
    if (t == 0) {
        int acc = 0;
        #pragma unroll
        for (int w = 0; w < 4; w++) { int tv = wsum[w]; wsum[w] = acc; acc += tv; }
    }
    __syncthreads();
    if (t < 256) {
        int base = dbase + wsum[wid] + (inc - s);
        cur[2 * t] = base;
        cur[2 * t + 1] = base + c0;
        int node0 = n0 + 2 * t;
        if (node0 < N_NODES) {
            rowstart[node0] = base;
            rowend[node0] = base + c0;
            dinv[node0] = rsqrtf((float)(c0 + 1));
        }
        if (node0 + 1 < N_NODES) {
            rowstart[node0 + 1] = base + c0;
            rowend[node0 + 1] = base + c0 + c1;
            dinv[node0 + 1] = rsqrtf((float)(c1 + 1));
        }
    }
    __syncthreads();

    for (int p = t; p < nt4; p += 1024) {
        uint4 e = arena4[p];
        #pragma unroll
        for (int j = 0; j < 4; j++) {
            unsigned entry = (j == 0) ? e.x : (j == 1) ? e.y : (j == 2) ? e.z : e.w;
            int local = (int)(entry >> 17);
            int sv = (int)(entry & 0x1FFFFu);
            int pos = atomicAdd(&cur[local], 1);
            csr[pos] = sv;
        }
    }
    {
        int p = (nt4 << 2) + t;
        if (p < total) {
            unsigned entry = arena[abase + p];
            int local = (int)(entry >> 17);
            int sv = (int)(entry & 0x1FFFFu);
            int pos = atomicAdd(&cur[local], 1);
            csr[pos] = sv;
        }
    }
}

// ---------------- W1 transpose to fp16 [col][KPAD] ----------------

__global__ void k_w1t(const float* __restrict__ W1, _Float16* __restrict__ w1t) {
    int idx = blockIdx.x * 256 + threadIdx.x;
    if (idx < HIDDEN * KPAD) {
        int c = idx / KPAD, k = idx - c * KPAD;
        float v = (k < IN_DIM) ? W1[k * HIDDEN + c] : 0.f;
        w1t[idx] = (_Float16)v;
    }
}

// ---------------- GEMM1 (f16 MFMA): h1s = dinv * (x @ W1), fp16 row-major out ----------
// v2: stage 64 x-rows (contiguous 64*165 floats) into LDS via coalesced float4 loads;
// A-fragments then read from LDS. Kills the 660-B-strided 64-line fan-out per A-load.

__global__ __launch_bounds__(256) void k_gemm1(const float* __restrict__ x,
                                               const _Float16* __restrict__ w1t,
                                               const float* __restrict__ dinv,
                                               _Float16* __restrict__ h1s) {
    __shared__ float xs[GROWS * IN_DIM];    // 42240 B
    int t = threadIdx.x;
    int wid = t >> 6, lane = t & 63;
    int row0 = blockIdx.x * GROWS;
    int nrows = N_NODES - row0; if (nrows > GROWS) nrows = GROWS;   // 100000%64=32, 32%16==0
    int nflt = nrows * IN_DIM;

    // coalesced stage: region [row0*165, +nflt) is contiguous; base is 16B-aligned
    const float4* xb4 = (const float4*)(x + (size_t)row0 * IN_DIM);
    float4* xs4 = (float4*)xs;
    int n4 = nflt >> 2;
    for (int i = t; i < n4; i += 256) xs4[i] = xb4[i];
    for (int i = (n4 << 2) + t; i < nflt; i += 256) xs[i] = x[(size_t)row0 * IN_DIM + i];
    __syncthreads();

    int mrow = wid * 16;                    // wave's first row within block
    if (mrow >= nrows) return;              // after syncthreads: safe
    int m = lane & 15;
    int quad = lane >> 4;
    const float* xrow = xs + (mrow + m) * IN_DIM;
    int grow = row0 + mrow;                 // global first row of this wave

    floatx4 acc[8];
    #pragma unroll
    for (int i = 0; i < 8; i++) acc[i] = (floatx4)(0.f);

    #pragma unroll
    for (int kc = 0; kc < 5; kc++) {
        int kb = kc * 32 + quad * 8;       // max 152; +7 = 159 < 165 -> always in-row
        half8_t a;
        #pragma unroll
        for (int j = 0; j < 8; j++) a[j] = (_Float16)xrow[kb + j];
        #pragma unroll
        for (int cb = 0; cb < 8; cb++) {
            int col = cb * 16 + m;
            half8_t bf = *(const half8_t*)&w1t[col * KPAD + kb];
            acc[cb] = __builtin_amdgcn_mfma_f32_16x16x32_f16(a, bf, acc[cb], 0, 0, 0);
        }
    }
    // K tail: 160..164 via 16x16x16 (k = quad*4 + j) -- guarded LDS reads
    {
        int kb = 160 + quad * 4;
        half4_t a;
        #pragma unroll
        for (int j = 0; j < 4; j++)
            a[j] = (kb + j < IN_DIM) ? (_Float16)xrow[kb + j] : (_Float16)0.f;
        #pragma unroll
        for (int cb = 0; cb < 8; cb++) {
            int col = cb * 16 + m;
            half4_t bf = *(const half4_t*)&w1t[col * KPAD + kb];
            acc[cb] = __builtin_amdgcn_mfma_f32_16x16x16f16(a, bf, acc[cb], 0, 0, 0);
        }
    }
    // epilogue: scale by dinv[row], store fp16 (C/D: col=lane&15, row=quad*4+reg)
    float dv[4];
    #pragma unroll
    for (int r = 0; r < 4; r++) dv[r] = dinv[grow + quad * 4 + r];
    #pragma unroll
    for (int cb = 0; cb < 8; cb++) {
        #pragma unroll
        for (int r = 0; r < 4; r++) {
            h1s[(size_t)(grow + quad * 4 + r) * HIDDEN + cb * 16 + m] =
                (_Float16)(acc[cb][r] * dv[r]);
        }
    }
}

// ---------------- Fused agg1 + bias + ReLU + W2 (128->2) ----------------
// r2-proven structure: one wave per node, 16 feature-lanes x 4 edge-slots,
// 16B/lane half8 gathers, 2-deep pipeline, cached csr loads.

__global__ __launch_bounds__(256) void k_agg1(const _Float16* __restrict__ h1,
                                              const int* __restrict__ rowstart,
                                              const int* __restrict__ rowend,
                                              const int* __restrict__ csr,
                                              const float* __restrict__ dinv,
                                              const float* __restrict__ b1,
                                              const float* __restrict__ W2,
                                              float2* __restrict__ h2s) {
    int wid = threadIdx.x >> 6, lane = threadIdx.x & 63;
    int el = lane & 15;        // feature slot: owns features el*8 .. el*8+7
    int es = lane >> 4;        // edge slot 0..3
    int node = blockIdx.x * 4 + wid;

    float acc[8];
    // self term counted once (edge-slot 0)
    {
        half8_t v = *(const half8_t*)(h1 + (size_t)node * HIDDEN + el * 8);
        #pragma unroll
        for (int j = 0; j < 8; j++) acc[j] = (es == 0) ? (float)v[j] : 0.f;
    }

    int p0 = rowstart[node], p1 = rowend[node];
    int p = p0 + es;
    // 2-deep unroll: 2 gathers (2 KB/wave) in flight
    for (; p + 4 < p1; p += 8) {
        int sA = csr[p];
        int sB = csr[p + 4];
        half8_t vA = *(const half8_t*)(h1 + (size_t)sA * HIDDEN + el * 8);
        half8_t vB = *(const half8_t*)(h1 + (size_t)sB * HIDDEN + el * 8);
        #pragma unroll
        for (int j = 0; j < 8; j++) acc[j] += (float)vA[j];
        #pragma unroll
        for (int j = 0; j < 8; j++) acc[j] += (float)vB[j];
    }
    if (p < p1) {
        int s = csr[p];
        half8_t v = *(const half8_t*)(h1 + (size_t)s * HIDDEN + el * 8);
        #pragma unroll
        for (int j = 0; j < 8; j++) acc[j] += (float)v[j];
    }

    // reduce across the 4 edge slots (lanes el, el+16, el+32, el+48)
    #pragma unroll
    for (int j = 0; j < 8; j++) {
        acc[j] += __shfl_xor(acc[j], 16);
        acc[j] += __shfl_xor(acc[j], 32);
    }

    float di = dinv[node];
    // z = relu(di*acc + b1), then partial dot with W2 (128x2)
    float4 bb0 = ((const float4*)b1)[el * 2];
    float4 bb1 = ((const float4*)b1)[el * 2 + 1];
    float bv[8] = {bb0.x, bb0.y, bb0.z, bb0.w, bb1.x, bb1.y, bb1.z, bb1.w};
    float a0 = 0.f, a1 = 0.f;
    #pragma unroll
    for (int j = 0; j < 8; j++) {
        float z = fmaf(di, acc[j], bv[j]);
        float r = fmaxf(z, 0.f);
        float2 w = ((const float2*)W2)[el * 8 + j];
        a0 = fmaf(r, w.x, a0);
        a1 = fmaf(r, w.y, a1);
    }
    #pragma unroll
    for (int off = 8; off; off >>= 1) {
        a0 += __shfl_xor(a0, off);
        a1 += __shfl_xor(a1, off);
    }
    if (lane == 0) h2s[node] = make_float2(di * a0, di * a1);
}

// ---------------- agg2: out = b2 + dinv_i*(h2s_i + sum h2s_src) ----------------
// 16 lanes per node (wave = 4 nodes): lane-parallel gathers + xor-shuffle reduce.

__global__ __launch_bounds__(256) void k_agg2(const float2* __restrict__ h2s,
                                              const int* __restrict__ rowstart,
                                              const int* __restrict__ rowend,
                                              const int* __restrict__ csr,
                                              const float* __restrict__ dinv,
                                              const float* __restrict__ b2,
                                              float2* __restrict__ out) {
    int wid = threadIdx.x >> 6, lane = threadIdx.x & 63;
    int sub = lane >> 4, el = lane & 15;
    int node = blockIdx.x * 16 + wid * 4 + sub;   // grid 6250 * 16 = 100000 exactly
    int p0 = rowstart[node], p1 = rowend[node];
    float ax = 0.f, ay = 0.f;
    for (int p = p0 + el; p < p1; p += 16) {
        float2 g = h2s[csr[p]];
        ax += g.x;
        ay += g.y;
    }
    #pragma unroll
    for (int off = 8; off; off >>= 1) {
        ax += __shfl_xor(ax, off);
        ay += __shfl_xor(ay, off);
    }
    if (el == 0) {
        float2 self = h2s[node];
        float di = dinv[node];
        out[node] = make_float2(fmaf(di, self.x + ax, b2[0]),
                                fmaf(di, self.y + ay, b2[1]));
    }
}

// ---------------- launch ----------------

extern "C" void kernel_launch(void* const* d_in, const int* in_sizes, int n_in,
                              void* d_out, int out_size, void* d_ws, size_t ws_size,
                              hipStream_t stream) {
    const float* x  = (const float*)d_in[0];
    const int*   ei = (const int*)d_in[1];
    const float* W1 = (const float*)d_in[2];
    const float* b1 = (const float*)d_in[3];
    const float* W2 = (const float*)d_in[4];
    const float* b2 = (const float*)d_in[5];
    float* out = (float*)d_out;

    const int* src = ei;
    const int* dst = ei + N_EDGES;

    char* ws = (char*)d_ws;
    size_t off = 0;
    auto alloc = [&](size_t bytes) -> void* {
        void* p = ws + off;
        off += (bytes + 255) & ~(size_t)255;
        return p;
    };
    _Float16* h1s      = (_Float16*)alloc((size_t)N_NODES * HIDDEN * 2);  // 25.6 MB
    float*    dinv     = (float*)   alloc((size_t)N_NODES * 4);
    int*      rowstart = (int*)     alloc((size_t)N_NODES * 4);
    int*      rowend   = (int*)     alloc((size_t)N_NODES * 4);
    int*      bcnt     = (int*)     alloc((size_t)NBKT * 4);
    unsigned* arena    = (unsigned*)alloc((size_t)NBKT * PADCAP * 4);     // 8.0 MB
    int*      csr      = (int*)     alloc((size_t)NBKT * PADCAP * 4);     // 8.0 MB padded
    _Float16* w1t      = (_Float16*)alloc((size_t)HIDDEN * KPAD * 2);     // 45 KB
    float2*   h2s      = (float2*)  alloc((size_t)N_NODES * 8);

    (void)hipMemsetAsync(bcnt, 0, (size_t)NBKT * 4, stream);
    k_w1t<<<(HIDDEN * KPAD + 255) / 256, 256, 0, stream>>>(W1, w1t);
    k_part2<<<NCHUNK, 512, 0, stream>>>(src, dst, bcnt, arena);
    k_sort4<<<NBKT, 1024, 0, stream>>>(arena, bcnt, csr, rowstart, rowend, dinv);
    k_gemm1<<<(N_NODES + GROWS - 1) / GROWS, 256, 0, stream>>>(x, w1t, dinv, h1s);
    k_agg1<<<N_NODES / 4, 256, 0, stream>>>(h1s, rowstart, rowend, csr, dinv, b1, W2, h2s);
    k_agg2<<<N_NODES / 16, 256, 0, stream>>>(h2s, rowstart, rowend, csr, dinv, b2, (float2*)out);
}